// Round 3
// baseline (1884.938 us; speedup 1.0000x reference)
//
#include <hip/hip_runtime.h>
#include <math.h>

// Round 3:
//  - Encode split into 3 XCD-aware kernels. Blocks map to XCD via linear
//    blockId % 8 (gridDim.x = 8 => XCD == blockIdx.x).
//      A: levels 6..13, level (6+i) pinned to XCD i  -> its 4 MB table is
//         exactly one XCD's L2 -> resident after warmup.
//      B: levels 14,15 split across 8 XCDs (4 XCDs per level, 1/4 points).
//      C: levels 0..5 (3.8 MB total tables -> resident in every L2).
//    4 points/thread -> 32 independent gathers in flight per thread.
//    Positions pre-packed into float4[] so per-XCD passes read 16 MB, not
//    the 76 B-strided x rows.
//  - MLP: 2 points/thread so each scalar weight-row load feeds 128 FMAs.
//
// Reference bug replicated: final trilerp is c0*(1-fz) + c1*fy (fy, not fz).

#define BLOCK 256

constexpr int      kNL[16] = {16,22,28,37,49,65,85,112,148,195,257,338,446,589,777,1025};
constexpr unsigned kSZ[16] = {4096u,10648u,21952u,50656u,117656u,274632u,
                              524288u,524288u,524288u,524288u,524288u,
                              524288u,524288u,524288u,524288u,524288u};

// ---------------- gather: one level, 4 points per thread ----------------
template<int L>
__device__ __forceinline__ void gather4(const float* __restrict__ x,
                                        const float4* __restrict__ pos4,
                                        const float* __restrict__ grids,
                                        float* __restrict__ enc,
                                        int n, int p0, int cnt)
{
    constexpr int R = kNL[L];
    constexpr unsigned S = kSZ[L];
    const float2* __restrict__ gl = (const float2*)(grids + (size_t)L * (524288*2));

    float fxa[4], fya[4], fza[4];
    unsigned idx[4][8];
    #pragma unroll
    for (int q = 0; q < 4; ++q) {
        if (q >= cnt) continue;
        float px, py, pz;
        if (pos4) { float4 p = pos4[p0+q]; px = p.x; py = p.y; pz = p.z; }
        else { const float* xr = x + (size_t)(p0+q)*19; px = xr[0]; py = xr[1]; pz = xr[2]; }
        const float Rf = (float)R;
        float ux = px*Rf, uy = py*Rf, uz = pz*Rf;
        float gx = floorf(ux), gy = floorf(uy), gz = floorf(uz);
        fxa[q] = ux-gx; fya[q] = uy-gy; fza[q] = uz-gz;
        int ix = (int)gx, iy = (int)gy, iz = (int)gz;
        #pragma unroll
        for (int j = 0; j < 8; ++j) {
            int ox = ix + ((j>>2)&1);
            int oy = iy + ((j>>1)&1);
            int oz = iz + (j&1);
            if (L <= 2) {
                idx[q][j] = (unsigned)((oz*(R*R) + oy*R + ox) % (int)S);
            } else {
                unsigned h = (unsigned)ox
                           ^ (unsigned)oy * 2654435761u
                           ^ (unsigned)oz * 805459861u;
                idx[q][j] = h % S;   // compile-time S -> magic mod
            }
        }
    }

    float2 v[4][8];
    #pragma unroll
    for (int q = 0; q < 4; ++q) {
        if (q >= cnt) continue;
        #pragma unroll
        for (int j = 0; j < 8; ++j) v[q][j] = gl[idx[q][j]];
    }

    float e0[4], e1[4];
    #pragma unroll
    for (int q = 0; q < 4; ++q) {
        if (q >= cnt) continue;
        const float fx = fxa[q], fy = fya[q], fz = fza[q];
        const float w0x = 1.f-fx, w0y = 1.f-fy, w0z = 1.f-fz;
        {
            float c00 = v[q][0].x*w0x + v[q][4].x*fx;
            float c01 = v[q][1].x*w0x + v[q][5].x*fx;
            float c10 = v[q][2].x*w0x + v[q][6].x*fx;
            float c11 = v[q][3].x*w0x + v[q][7].x*fx;
            float c0 = c00*w0y + c10*fy;
            float c1 = c01*w0y + c11*fy;
            e0[q] = c0*w0z + c1*fy;   // reference bug: fy
        }
        {
            float c00 = v[q][0].y*w0x + v[q][4].y*fx;
            float c01 = v[q][1].y*w0x + v[q][5].y*fx;
            float c10 = v[q][2].y*w0x + v[q][6].y*fx;
            float c11 = v[q][3].y*w0x + v[q][7].y*fx;
            float c0 = c00*w0y + c10*fy;
            float c1 = c01*w0y + c11*fy;
            e1[q] = c0*w0z + c1*fy;   // reference bug: fy
        }
    }

    float* d0 = enc + (size_t)(2*L)*n   + p0;
    float* d1 = enc + (size_t)(2*L+1)*n + p0;
    if (cnt == 4) {
        *(float4*)d0 = make_float4(e0[0], e0[1], e0[2], e0[3]);
        *(float4*)d1 = make_float4(e1[0], e1[1], e1[2], e1[3]);
    } else {
        for (int q = 0; q < cnt; ++q) { d0[q] = e0[q]; d1[q] = e1[q]; }
    }
}

__global__ void pack_pos(const float* __restrict__ x, float4* __restrict__ pos4, int n)
{
    int i = blockIdx.x * BLOCK + threadIdx.x;
    if (i >= n) return;
    const float* xr = x + (size_t)i * 19;
    pos4[i] = make_float4(xr[0], xr[1], xr[2], 0.f);
}

// A: levels 6..13, level (6+bx) on XCD bx
__global__ __launch_bounds__(BLOCK)
void enc_A(const float* __restrict__ x, const float4* __restrict__ pos4,
           const float* __restrict__ grids, float* __restrict__ enc, int n)
{
    int p0 = (blockIdx.y * BLOCK + threadIdx.x) * 4;
    if (p0 >= n) return;
    int cnt = min(4, n - p0);
    switch (blockIdx.x) {
        case 0: gather4< 6>(x,pos4,grids,enc,n,p0,cnt); break;
        case 1: gather4< 7>(x,pos4,grids,enc,n,p0,cnt); break;
        case 2: gather4< 8>(x,pos4,grids,enc,n,p0,cnt); break;
        case 3: gather4< 9>(x,pos4,grids,enc,n,p0,cnt); break;
        case 4: gather4<10>(x,pos4,grids,enc,n,p0,cnt); break;
        case 5: gather4<11>(x,pos4,grids,enc,n,p0,cnt); break;
        case 6: gather4<12>(x,pos4,grids,enc,n,p0,cnt); break;
        case 7: gather4<13>(x,pos4,grids,enc,n,p0,cnt); break;
    }
}

// B: level 14 on XCDs 0..3, level 15 on XCDs 4..7, quarter of points each
__global__ __launch_bounds__(BLOCK)
void enc_B(const float* __restrict__ x, const float4* __restrict__ pos4,
           const float* __restrict__ grids, float* __restrict__ enc, int n)
{
    int quarter = blockIdx.x & 3;
    int q = (n + 3) / 4;
    int jobBase = quarter * q;
    int jobEnd  = min(n, jobBase + q);
    int p0 = jobBase + (blockIdx.y * BLOCK + threadIdx.x) * 4;
    if (p0 >= jobEnd) return;
    int cnt = min(4, jobEnd - p0);
    if (blockIdx.x < 4) gather4<14>(x,pos4,grids,enc,n,p0,cnt);
    else                gather4<15>(x,pos4,grids,enc,n,p0,cnt);
}

// C: levels 0..5 (3.8 MB of tables -> resident everywhere)
__global__ __launch_bounds__(BLOCK)
void enc_C(const float* __restrict__ x, const float4* __restrict__ pos4,
           const float* __restrict__ grids, float* __restrict__ enc, int n)
{
    int p0 = (blockIdx.y * BLOCK + threadIdx.x) * 4;
    if (p0 >= n) return;
    int cnt = min(4, n - p0);
    switch (blockIdx.x) {
        case 0: gather4<0>(x,pos4,grids,enc,n,p0,cnt); break;
        case 1: gather4<1>(x,pos4,grids,enc,n,p0,cnt); break;
        case 2: gather4<2>(x,pos4,grids,enc,n,p0,cnt); break;
        case 3: gather4<3>(x,pos4,grids,enc,n,p0,cnt); break;
        case 4: gather4<4>(x,pos4,grids,enc,n,p0,cnt); break;
        case 5: gather4<5>(x,pos4,grids,enc,n,p0,cnt); break;
    }
}

// ---------------- MLP: 2 points per thread ----------------
__global__ __launch_bounds__(BLOCK)
void mlp_kernel(const float* __restrict__ x,
                const float* __restrict__ enc,
                const float* __restrict__ w1,   // (32,64)
                const float* __restrict__ w2,   // (64,16)
                const float* __restrict__ wc1,  // (32,64)
                const float* __restrict__ wc2,  // (64,64)
                const float* __restrict__ wc3,  // (64,3)
                float* __restrict__ out, int n)
{
    __shared__ float s_x[512 * 19];
    const int t = threadIdx.x;
    const int base = blockIdx.x * 512;
    {
        const float* xb = x + (size_t)base * 19;
        int limit = (n - base) * 19;
        if (limit > 512*19) limit = 512*19;
        for (int i = t; i < 512*19; i += BLOCK)
            if (i < limit) s_x[i] = xb[i];
    }
    __syncthreads();

    const int pA = base + t;
    const int pB = base + 256 + t;
    if (pA >= n) return;
    const bool haveB = (pB < n);
    const int pBc = haveB ? pB : pA;
    const int tB  = haveB ? (t + 256) : t;

    // ---- layer 1: h = relu(enc @ w1), enc in two k-chunks of 16 ----
    float hA[64], hB[64];
    #pragma unroll
    for (int j = 0; j < 64; ++j) { hA[j] = 0.f; hB[j] = 0.f; }
    #pragma unroll
    for (int kc = 0; kc < 32; kc += 16) {
        float eA[16], eB[16];
        #pragma unroll
        for (int k = 0; k < 16; ++k) {
            eA[k] = enc[(size_t)(kc+k) * n + pA];
            eB[k] = enc[(size_t)(kc+k) * n + pBc];
        }
        for (int k = 0; k < 16; ++k) {
            const float* wr = w1 + (kc+k)*64;   // uniform -> s_load
            float aA = eA[k], aB = eB[k];
            #pragma unroll
            for (int j = 0; j < 64; ++j) {
                hA[j] = fmaf(aA, wr[j], hA[j]);
                hB[j] = fmaf(aB, wr[j], hB[j]);
            }
        }
    }
    #pragma unroll
    for (int j = 0; j < 64; ++j) { hA[j] = fmaxf(hA[j], 0.f); hB[j] = fmaxf(hB[j], 0.f); }

    // ---- layer 2: o = h @ w2 (no relu; o[0] = sigma) ----
    float oA[16], oB[16];
    #pragma unroll
    for (int j = 0; j < 16; ++j) { oA[j] = 0.f; oB[j] = 0.f; }
    for (int k = 0; k < 64; ++k) {
        const float* wr = w2 + k*16;
        float aA = hA[k], aB = hB[k];
        #pragma unroll
        for (int j = 0; j < 16; ++j) {
            oA[j] = fmaf(aA, wr[j], oA[j]);
            oB[j] = fmaf(aB, wr[j], oB[j]);
        }
    }
    const float sigmaA = oA[0], sigmaB = oB[0];

    // ---- color layer 1: hc = relu([direc, o] @ wc1) (reuse h arrays) ----
    #pragma unroll
    for (int j = 0; j < 64; ++j) { hA[j] = 0.f; hB[j] = 0.f; }
    for (int k = 0; k < 16; ++k) {
        const float* wr = wc1 + k*64;
        float aA = s_x[t*19 + 3 + k];
        float aB = s_x[tB*19 + 3 + k];
        #pragma unroll
        for (int j = 0; j < 64; ++j) {
            hA[j] = fmaf(aA, wr[j], hA[j]);
            hB[j] = fmaf(aB, wr[j], hB[j]);
        }
    }
    for (int k = 0; k < 16; ++k) {
        const float* wr = wc1 + (16+k)*64;
        float aA = oA[k], aB = oB[k];
        #pragma unroll
        for (int j = 0; j < 64; ++j) {
            hA[j] = fmaf(aA, wr[j], hA[j]);
            hB[j] = fmaf(aB, wr[j], hB[j]);
        }
    }
    #pragma unroll
    for (int j = 0; j < 64; ++j) { hA[j] = fmaxf(hA[j], 0.f); hB[j] = fmaxf(hB[j], 0.f); }

    // ---- color layers 2+3 fused, two 32-wide halves ----
    float c0A = 0.f, c1A = 0.f, c2A = 0.f;
    float c0B = 0.f, c1B = 0.f, c2B = 0.f;
    #pragma unroll
    for (int half = 0; half < 2; ++half) {
        float gA[32], gB[32];
        #pragma unroll
        for (int j = 0; j < 32; ++j) { gA[j] = 0.f; gB[j] = 0.f; }
        for (int k = 0; k < 64; ++k) {
            const float* wr = wc2 + k*64 + half*32;
            float aA = hA[k], aB = hB[k];
            #pragma unroll
            for (int j = 0; j < 32; ++j) {
                gA[j] = fmaf(aA, wr[j], gA[j]);
                gB[j] = fmaf(aB, wr[j], gB[j]);
            }
        }
        const float* w3 = wc3 + half*32*3;
        #pragma unroll
        for (int j = 0; j < 32; ++j) {
            float vA = fmaxf(gA[j], 0.f);
            float vB = fmaxf(gB[j], 0.f);
            c0A = fmaf(vA, w3[j*3+0], c0A);
            c1A = fmaf(vA, w3[j*3+1], c1A);
            c2A = fmaf(vA, w3[j*3+2], c2A);
            c0B = fmaf(vB, w3[j*3+0], c0B);
            c1B = fmaf(vB, w3[j*3+1], c1B);
            c2B = fmaf(vB, w3[j*3+2], c2B);
        }
    }

    float4 rA, rB;
    rA.x = 1.f / (1.f + __expf(-c0A));
    rA.y = 1.f / (1.f + __expf(-c1A));
    rA.z = 1.f / (1.f + __expf(-c2A));
    rA.w = sigmaA;
    rB.x = 1.f / (1.f + __expf(-c0B));
    rB.y = 1.f / (1.f + __expf(-c1B));
    rB.z = 1.f / (1.f + __expf(-c2B));
    rB.w = sigmaB;
    ((float4*)out)[pA] = rA;
    if (haveB) ((float4*)out)[pB] = rB;
}

extern "C" void kernel_launch(void* const* d_in, const int* in_sizes, int n_in,
                              void* d_out, int out_size, void* d_ws, size_t ws_size,
                              hipStream_t stream) {
    const float* x     = (const float*)d_in[0];
    const float* grids = (const float*)d_in[1];
    const float* w1    = (const float*)d_in[2];
    const float* w2    = (const float*)d_in[3];
    const float* wc1   = (const float*)d_in[4];
    const float* wc2   = (const float*)d_in[5];
    const float* wc3   = (const float*)d_in[6];
    float* out = (float*)d_out;

    int n = in_sizes[0] / 19;
    size_t encBytes = (size_t)32 * n * sizeof(float);
    float* enc = (float*)d_ws;
    bool use_pos = (ws_size >= encBytes + (size_t)n * sizeof(float4));
    float4* pos4 = use_pos ? (float4*)((char*)d_ws + encBytes) : nullptr;

    if (use_pos)
        pack_pos<<<(n + BLOCK - 1) / BLOCK, BLOCK, 0, stream>>>(x, pos4, n);

    int nthread4 = (n + 3) / 4;                       // threads needed at 4 pts/thread
    int by  = (nthread4 + BLOCK - 1) / BLOCK;
    dim3 gA(8, by);
    enc_A<<<gA, BLOCK, 0, stream>>>(x, pos4, grids, enc, n);

    int q = (n + 3) / 4;
    int byB = ((q + 3) / 4 + BLOCK - 1) / BLOCK;
    dim3 gB(8, byB);
    enc_B<<<gB, BLOCK, 0, stream>>>(x, pos4, grids, enc, n);

    dim3 gC(6, by);
    enc_C<<<gC, BLOCK, 0, stream>>>(x, pos4, grids, enc, n);

    mlp_kernel<<<(n + 511) / 512, BLOCK, 0, stream>>>(x, enc, w1, w2, wc1, wc2, wc3, out, n);
}

// Round 4
// 906.500 us; speedup vs baseline: 2.0794x; 2.0794x over previous
//
#include <hip/hip_runtime.h>
#include <math.h>

// Round 4:
//  - Encode: round-3 XCD-pinned split kernels, but tables pre-converted to
//    bf16 in ws (hashed level = 2 MB -> fits pinned XCD L2 with headroom).
//  - MLP: MFMA (16x16x32 bf16). 4 waves/block, 16 pts/wave. Weights live in
//    VGPR B-frags. Inter-layer C->A layout via per-wave LDS transpose
//    (pitch 65 => 2-way bank aliasing = free). Color-path activations use
//    hi/lo bf16 split (error becomes weight-quantization only).
// Reference bug replicated: final trilerp is c0*(1-fz) + c1*fy (fy, not fz).

#define BLOCK 256
#define NTAB  (16*524288)

constexpr int      kNL[16] = {16,22,28,37,49,65,85,112,148,195,257,338,446,589,777,1025};
constexpr unsigned kSZ[16] = {4096u,10648u,21952u,50656u,117656u,274632u,
                              524288u,524288u,524288u,524288u,524288u,
                              524288u,524288u,524288u,524288u,524288u};

typedef __attribute__((ext_vector_type(8))) short short8;
typedef __attribute__((ext_vector_type(4))) float float4v;

__device__ __forceinline__ short f2bf(float f) {
    unsigned u = __float_as_uint(f);
    unsigned r = u + 0x7fffu + ((u >> 16) & 1u);   // RNE
    return (short)(r >> 16);
}
__device__ __forceinline__ float bf2f(short h) {
    return __uint_as_float(((unsigned)(unsigned short)h) << 16);
}

// ================= prep kernels =================
__global__ void pack_pos(const float* __restrict__ x, float4* __restrict__ pos4, int n)
{
    int i = blockIdx.x * BLOCK + threadIdx.x;
    if (i >= n) return;
    const float* xr = x + (size_t)i * 19;
    pos4[i] = make_float4(xr[0], xr[1], xr[2], 0.f);
}

__global__ void conv_tables(const float* __restrict__ grids, ushort2* __restrict__ tbf)
{
    int i = blockIdx.x * BLOCK + threadIdx.x;
    if (i >= NTAB) return;
    float2 v = ((const float2*)grids)[i];
    ushort2 o;
    o.x = (unsigned short)f2bf(v.x);
    o.y = (unsigned short)f2bf(v.y);
    tbf[i] = o;
}

// ================= encode =================
template<int L, bool BF>
__device__ __forceinline__ float2 tload(const float* __restrict__ grids,
                                        const ushort2* __restrict__ tbf, unsigned idx)
{
    if (BF) {
        ushort2 r = tbf[(size_t)L * 524288u + idx];
        return make_float2(__uint_as_float((unsigned)r.x << 16),
                           __uint_as_float((unsigned)r.y << 16));
    } else {
        const float2* gl = (const float2*)(grids + (size_t)L * (524288*2));
        return gl[idx];
    }
}

template<int L, bool BF>
__device__ __forceinline__ void gather4(const float* __restrict__ x,
                                        const float4* __restrict__ pos4,
                                        const float* __restrict__ grids,
                                        const ushort2* __restrict__ tbf,
                                        float* __restrict__ enc,
                                        int n, int p0, int cnt)
{
    constexpr int R = kNL[L];
    constexpr unsigned S = kSZ[L];

    float fxa[4], fya[4], fza[4];
    unsigned idx[4][8];
    #pragma unroll
    for (int q = 0; q < 4; ++q) {
        if (q >= cnt) continue;
        float px, py, pz;
        if (pos4) { float4 p = pos4[p0+q]; px = p.x; py = p.y; pz = p.z; }
        else { const float* xr = x + (size_t)(p0+q)*19; px = xr[0]; py = xr[1]; pz = xr[2]; }
        const float Rf = (float)R;
        float ux = px*Rf, uy = py*Rf, uz = pz*Rf;
        float gx = floorf(ux), gy = floorf(uy), gz = floorf(uz);
        fxa[q] = ux-gx; fya[q] = uy-gy; fza[q] = uz-gz;
        int ix = (int)gx, iy = (int)gy, iz = (int)gz;
        #pragma unroll
        for (int j = 0; j < 8; ++j) {
            int ox = ix + ((j>>2)&1);
            int oy = iy + ((j>>1)&1);
            int oz = iz + (j&1);
            if (L <= 2) {
                idx[q][j] = (unsigned)((oz*(R*R) + oy*R + ox) % (int)S);
            } else {
                unsigned h = (unsigned)ox
                           ^ (unsigned)oy * 2654435761u
                           ^ (unsigned)oz * 805459861u;
                idx[q][j] = h % S;
            }
        }
    }

    float2 v[4][8];
    #pragma unroll
    for (int q = 0; q < 4; ++q) {
        if (q >= cnt) continue;
        #pragma unroll
        for (int j = 0; j < 8; ++j) v[q][j] = tload<L,BF>(grids, tbf, idx[q][j]);
    }

    float e0[4], e1[4];
    #pragma unroll
    for (int q = 0; q < 4; ++q) {
        if (q >= cnt) continue;
        const float fx = fxa[q], fy = fya[q], fz = fza[q];
        const float w0x = 1.f-fx, w0y = 1.f-fy, w0z = 1.f-fz;
        {
            float c00 = v[q][0].x*w0x + v[q][4].x*fx;
            float c01 = v[q][1].x*w0x + v[q][5].x*fx;
            float c10 = v[q][2].x*w0x + v[q][6].x*fx;
            float c11 = v[q][3].x*w0x + v[q][7].x*fx;
            float c0 = c00*w0y + c10*fy;
            float c1 = c01*w0y + c11*fy;
            e0[q] = c0*w0z + c1*fy;   // reference bug: fy
        }
        {
            float c00 = v[q][0].y*w0x + v[q][4].y*fx;
            float c01 = v[q][1].y*w0x + v[q][5].y*fx;
            float c10 = v[q][2].y*w0x + v[q][6].y*fx;
            float c11 = v[q][3].y*w0x + v[q][7].y*fx;
            float c0 = c00*w0y + c10*fy;
            float c1 = c01*w0y + c11*fy;
            e1[q] = c0*w0z + c1*fy;   // reference bug: fy
        }
    }

    float* d0 = enc + (size_t)(2*L)*n   + p0;
    float* d1 = enc + (size_t)(2*L+1)*n + p0;
    if (cnt == 4) {
        *(float4*)d0 = make_float4(e0[0], e0[1], e0[2], e0[3]);
        *(float4*)d1 = make_float4(e1[0], e1[1], e1[2], e1[3]);
    } else {
        for (int q = 0; q < cnt; ++q) { d0[q] = e0[q]; d1[q] = e1[q]; }
    }
}

template<bool BF>
__global__ __launch_bounds__(BLOCK)
void enc_A(const float* __restrict__ x, const float4* __restrict__ pos4,
           const float* __restrict__ grids, const ushort2* __restrict__ tbf,
           float* __restrict__ enc, int n)
{
    int p0 = (blockIdx.y * BLOCK + threadIdx.x) * 4;
    if (p0 >= n) return;
    int cnt = min(4, n - p0);
    switch (blockIdx.x) {
        case 0: gather4< 6,BF>(x,pos4,grids,tbf,enc,n,p0,cnt); break;
        case 1: gather4< 7,BF>(x,pos4,grids,tbf,enc,n,p0,cnt); break;
        case 2: gather4< 8,BF>(x,pos4,grids,tbf,enc,n,p0,cnt); break;
        case 3: gather4< 9,BF>(x,pos4,grids,tbf,enc,n,p0,cnt); break;
        case 4: gather4<10,BF>(x,pos4,grids,tbf,enc,n,p0,cnt); break;
        case 5: gather4<11,BF>(x,pos4,grids,tbf,enc,n,p0,cnt); break;
        case 6: gather4<12,BF>(x,pos4,grids,tbf,enc,n,p0,cnt); break;
        case 7: gather4<13,BF>(x,pos4,grids,tbf,enc,n,p0,cnt); break;
    }
}

template<bool BF>
__global__ __launch_bounds__(BLOCK)
void enc_B(const float* __restrict__ x, const float4* __restrict__ pos4,
           const float* __restrict__ grids, const ushort2* __restrict__ tbf,
           float* __restrict__ enc, int n)
{
    int quarter = blockIdx.x & 3;
    int q = (n + 3) / 4;
    int jobBase = quarter * q;
    int jobEnd  = min(n, jobBase + q);
    int p0 = jobBase + (blockIdx.y * BLOCK + threadIdx.x) * 4;
    if (p0 >= jobEnd) return;
    int cnt = min(4, jobEnd - p0);
    if (blockIdx.x < 4) gather4<14,BF>(x,pos4,grids,tbf,enc,n,p0,cnt);
    else                gather4<15,BF>(x,pos4,grids,tbf,enc,n,p0,cnt);
}

template<bool BF>
__global__ __launch_bounds__(BLOCK)
void enc_C(const float* __restrict__ x, const float4* __restrict__ pos4,
           const float* __restrict__ grids, const ushort2* __restrict__ tbf,
           float* __restrict__ enc, int n)
{
    int p0 = (blockIdx.y * BLOCK + threadIdx.x) * 4;
    if (p0 >= n) return;
    int cnt = min(4, n - p0);
    switch (blockIdx.x) {
        case 0: gather4<0,BF>(x,pos4,grids,tbf,enc,n,p0,cnt); break;
        case 1: gather4<1,BF>(x,pos4,grids,tbf,enc,n,p0,cnt); break;
        case 2: gather4<2,BF>(x,pos4,grids,tbf,enc,n,p0,cnt); break;
        case 3: gather4<3,BF>(x,pos4,grids,tbf,enc,n,p0,cnt); break;
        case 4: gather4<4,BF>(x,pos4,grids,tbf,enc,n,p0,cnt); break;
        case 5: gather4<5,BF>(x,pos4,grids,tbf,enc,n,p0,cnt); break;
    }
}

// ================= MFMA MLP =================
// Wave handles 16 points. A-frag: A[m][k], m=lane&15, k=(lane>>4)*8+j.
// B-frag: B[k][n], n=lane&15, k=(lane>>4)*8+j.
// C/D:    C[row][col], col=lane&15, row=(lane>>4)*4+r.
__global__ __launch_bounds__(BLOCK)
void mlp_mfma(const float* __restrict__ x,
              const float* __restrict__ enc,
              const float* __restrict__ w1,   // (32,64)
              const float* __restrict__ w2,   // (64,16)
              const float* __restrict__ wc1,  // (32,64)
              const float* __restrict__ wc2,  // (64,64)
              const float* __restrict__ wc3,  // (64,3)
              float* __restrict__ out, int n)
{
    __shared__ float s_enc[32*66];      // [feat][pt-in-block], pitch 66
    __shared__ float s_scr[4][16*65];   // per-wave transpose scratch, pitch 65

    const int t    = threadIdx.x;
    const int lane = t & 63;
    const int wave = t >> 6;
    const int blk  = blockIdx.x * 64;

    // ---- stage enc tile [32 feats][64 pts] (n assumed %64==0; true here) ----
    for (int idx = t; idx < 32*16; idx += BLOCK) {
        int f = idx >> 4, i = idx & 15;
        float4 v = ((const float4*)enc)[(size_t)f*(n>>2) + (blk>>2) + i];
        s_enc[f*66 + i*4 + 0] = v.x;
        s_enc[f*66 + i*4 + 1] = v.y;
        s_enc[f*66 + i*4 + 2] = v.z;
        s_enc[f*66 + i*4 + 3] = v.w;
    }
    __syncthreads();

    const int m  = lane & 15;     // point-in-16 / row
    const int q  = lane >> 4;     // quad
    const int cn = m;             // col for B/C frags
    const int pt = blk + wave*16 + m;
    const int ptc = pt < n ? pt : n-1;

    // ---- weights -> B-frags (per wave, held in VGPRs) ----
    short8 bw1[4], bwc1[4], bwc2[2][4], bw2[2], bwc3[2];
    #pragma unroll
    for (int nt = 0; nt < 4; ++nt)
        #pragma unroll
        for (int j = 0; j < 8; ++j) {
            bw1 [nt][j] = f2bf(w1 [(q*8+j)*64 + nt*16 + cn]);
            bwc1[nt][j] = f2bf(wc1[(q*8+j)*64 + nt*16 + cn]);
        }
    #pragma unroll
    for (int c = 0; c < 2; ++c) {
        #pragma unroll
        for (int nt = 0; nt < 4; ++nt)
            #pragma unroll
            for (int j = 0; j < 8; ++j)
                bwc2[c][nt][j] = f2bf(wc2[(c*32 + q*8+j)*64 + nt*16 + cn]);
        #pragma unroll
        for (int j = 0; j < 8; ++j) {
            bw2 [c][j] = f2bf(w2[(c*32 + q*8+j)*16 + cn]);
            bwc3[c][j] = (cn < 3) ? f2bf(wc3[(c*32 + q*8+j)*3 + cn]) : (short)0;
        }
    }

    const float4v zero = {0.f, 0.f, 0.f, 0.f};
    float* scr = &s_scr[wave][0];

    // ---- L1: h(16x64) = relu(enc @ w1) ----
    short8 a1;
    #pragma unroll
    for (int j = 0; j < 8; ++j)
        a1[j] = f2bf(s_enc[(q*8+j)*66 + wave*16 + m]);
    float4v h[4];
    #pragma unroll
    for (int nt = 0; nt < 4; ++nt) {
        h[nt] = __builtin_amdgcn_mfma_f32_16x16x32_bf16(a1, bw1[nt], zero, 0, 0, 0);
        #pragma unroll
        for (int r = 0; r < 4; ++r) h[nt][r] = fmaxf(h[nt][r], 0.f);
    }

    // transpose h -> scr[pt][feat]
    #pragma unroll
    for (int nt = 0; nt < 4; ++nt)
        #pragma unroll
        for (int r = 0; r < 4; ++r)
            scr[(q*4+r)*65 + nt*16 + cn] = h[nt][r];

    short8 ah[2];
    #pragma unroll
    for (int c = 0; c < 2; ++c)
        #pragma unroll
        for (int j = 0; j < 8; ++j)
            ah[c][j] = f2bf(scr[m*65 + c*32 + q*8 + j]);

    // ---- L2: o(16x16) = h @ w2 (no relu) ----
    float4v o = __builtin_amdgcn_mfma_f32_16x16x32_bf16(ah[0], bw2[0], zero, 0, 0, 0);
    o = __builtin_amdgcn_mfma_f32_16x16x32_bf16(ah[1], bw2[1], o, 0, 0, 0);

    // o -> scr[pt][0..15]; grab sigma = o[:,0]
    #pragma unroll
    for (int r = 0; r < 4; ++r)
        scr[(q*4+r)*65 + cn] = o[r];
    const float sigma = scr[m*65 + 0];

    // ---- CL1: hc(16x64) = relu([direc,o] @ wc1), direc split hi/lo ----
    short8 ci_hi, ci_lo;
    if (q < 2) {
        #pragma unroll
        for (int j = 0; j < 8; ++j) {
            float d = x[(size_t)ptc*19 + 3 + q*8 + j];
            short hi = f2bf(d);
            ci_hi[j] = hi;
            ci_lo[j] = f2bf(d - bf2f(hi));
        }
    } else {
        #pragma unroll
        for (int j = 0; j < 8; ++j) {
            float ov = scr[m*65 + (q-2)*8 + j];
            ci_hi[j] = f2bf(ov);
            ci_lo[j] = 0;
        }
    }
    float4v hc[4];
    #pragma unroll
    for (int nt = 0; nt < 4; ++nt) {
        hc[nt] = __builtin_amdgcn_mfma_f32_16x16x32_bf16(ci_hi, bwc1[nt], zero, 0, 0, 0);
        hc[nt] = __builtin_amdgcn_mfma_f32_16x16x32_bf16(ci_lo, bwc1[nt], hc[nt], 0, 0, 0);
        #pragma unroll
        for (int r = 0; r < 4; ++r) hc[nt][r] = fmaxf(hc[nt][r], 0.f);
    }

    // transpose hc -> scr; read back hi/lo A-frags
    #pragma unroll
    for (int nt = 0; nt < 4; ++nt)
        #pragma unroll
        for (int r = 0; r < 4; ++r)
            scr[(q*4+r)*65 + nt*16 + cn] = hc[nt][r];
    short8 ghi[2], glo[2];
    #pragma unroll
    for (int c = 0; c < 2; ++c)
        #pragma unroll
        for (int j = 0; j < 8; ++j) {
            float v = scr[m*65 + c*32 + q*8 + j];
            short hi = f2bf(v);
            ghi[c][j] = hi;
            glo[c][j] = f2bf(v - bf2f(hi));
        }

    // ---- CL2: g(16x64) = relu(hc @ wc2) ----
    float4v g[4];
    #pragma unroll
    for (int nt = 0; nt < 4; ++nt) {
        float4v acc = __builtin_amdgcn_mfma_f32_16x16x32_bf16(ghi[0], bwc2[0][nt], zero, 0, 0, 0);
        acc = __builtin_amdgcn_mfma_f32_16x16x32_bf16(glo[0], bwc2[0][nt], acc, 0, 0, 0);
        acc = __builtin_amdgcn_mfma_f32_16x16x32_bf16(ghi[1], bwc2[1][nt], acc, 0, 0, 0);
        acc = __builtin_amdgcn_mfma_f32_16x16x32_bf16(glo[1], bwc2[1][nt], acc, 0, 0, 0);
        #pragma unroll
        for (int r = 0; r < 4; ++r) acc[r] = fmaxf(acc[r], 0.f);
        g[nt] = acc;
    }

    // transpose g -> scr; read back hi/lo
    #pragma unroll
    for (int nt = 0; nt < 4; ++nt)
        #pragma unroll
        for (int r = 0; r < 4; ++r)
            scr[(q*4+r)*65 + nt*16 + cn] = g[nt][r];
    short8 uhi[2], ulo[2];
    #pragma unroll
    for (int c = 0; c < 2; ++c)
        #pragma unroll
        for (int j = 0; j < 8; ++j) {
            float v = scr[m*65 + c*32 + q*8 + j];
            short hi = f2bf(v);
            uhi[c][j] = hi;
            ulo[c][j] = f2bf(v - bf2f(hi));
        }

    // ---- CL3: colors = sigmoid(g @ wc3) ----
    float4v col = __builtin_amdgcn_mfma_f32_16x16x32_bf16(uhi[0], bwc3[0], zero, 0, 0, 0);
    col = __builtin_amdgcn_mfma_f32_16x16x32_bf16(ulo[0], bwc3[0], col, 0, 0, 0);
    col = __builtin_amdgcn_mfma_f32_16x16x32_bf16(uhi[1], bwc3[1], col, 0, 0, 0);
    col = __builtin_amdgcn_mfma_f32_16x16x32_bf16(ulo[1], bwc3[1], col, 0, 0, 0);
    #pragma unroll
    for (int r = 0; r < 4; ++r)
        col[r] = 1.f / (1.f + __expf(-col[r]));

    // colors -> scr[pt][col]; lanes of quad 0 store float4 per point
    #pragma unroll
    for (int r = 0; r < 4; ++r)
        scr[(q*4+r)*65 + cn] = col[r];
    if (q == 0 && pt < n) {
        float4 res;
        res.x = scr[m*65 + 0];
        res.y = scr[m*65 + 1];
        res.z = scr[m*65 + 2];
        res.w = sigma;
        ((float4*)out)[pt] = res;
    }
}

// ================= launch =================
extern "C" void kernel_launch(void* const* d_in, const int* in_sizes, int n_in,
                              void* d_out, int out_size, void* d_ws, size_t ws_size,
                              hipStream_t stream) {
    const float* x     = (const float*)d_in[0];
    const float* grids = (const float*)d_in[1];
    const float* w1    = (const float*)d_in[2];
    const float* w2    = (const float*)d_in[3];
    const float* wc1   = (const float*)d_in[4];
    const float* wc2   = (const float*)d_in[5];
    const float* wc3   = (const float*)d_in[6];
    float* out = (float*)d_out;

    int n = in_sizes[0] / 19;
    size_t encB = (size_t)32 * n * sizeof(float);
    size_t posB = (size_t)n * sizeof(float4);
    size_t tabB = (size_t)NTAB * sizeof(ushort2);

    char* p = (char*)d_ws;
    float* enc = (float*)p;
    bool has_pos = ws_size >= encB + posB;
    float4* pos4 = has_pos ? (float4*)(p + encB) : nullptr;
    bool has_tab = has_pos && (ws_size >= encB + posB + tabB);
    ushort2* tbf = has_tab ? (ushort2*)(p + encB + posB) : nullptr;

    if (has_pos)
        pack_pos<<<(n + BLOCK - 1) / BLOCK, BLOCK, 0, stream>>>(x, pos4, n);
    if (has_tab)
        conv_tables<<<(NTAB + BLOCK - 1) / BLOCK, BLOCK, 0, stream>>>(grids, tbf);

    int nthread4 = (n + 3) / 4;
    int by  = (nthread4 + BLOCK - 1) / BLOCK;
    int qq = (n + 3) / 4;
    int byB = ((qq + 3) / 4 + BLOCK - 1) / BLOCK;

    if (has_tab) {
        enc_A<true><<<dim3(8, by),  BLOCK, 0, stream>>>(x, pos4, grids, tbf, enc, n);
        enc_B<true><<<dim3(8, byB), BLOCK, 0, stream>>>(x, pos4, grids, tbf, enc, n);
        enc_C<true><<<dim3(6, by),  BLOCK, 0, stream>>>(x, pos4, grids, tbf, enc, n);
    } else {
        enc_A<false><<<dim3(8, by),  BLOCK, 0, stream>>>(x, pos4, grids, tbf, enc, n);
        enc_B<false><<<dim3(8, byB), BLOCK, 0, stream>>>(x, pos4, grids, tbf, enc, n);
        enc_C<false><<<dim3(6, by),  BLOCK, 0, stream>>>(x, pos4, grids, tbf, enc, n);
    }

    mlp_mfma<<<(n + 63) / 64, BLOCK, 0, stream>>>(x, enc, w1, w2, wc1, wc2, wc3, out, n);
}

// Round 5
// 735.138 us; speedup vs baseline: 2.5641x; 1.2331x over previous
//
#include <hip/hip_runtime.h>
#include <math.h>

// Round 5:
//  - Encode: unchanged XCD-pinned bf16-table kernels, but output enc as bf16
//    level-planes: enc[L][pt] = ushort2(feat 2L, feat 2L+1) -> one dword per
//    (level, point). MLP A-frags become 4 raw dword loads (zero conversion).
//  - MLP: weight B-frags pre-packed to bf16 in ws by a tiny prep kernel
//    (20 uint4 coalesced loads/lane replaces ~224 scalar loads + f2bf).
//    Inter-layer transposes via per-wave LDS ushort planes, pitch 88
//    (16B-aligned ds_read_b128 -> short8 direct).
// Reference bug replicated: final trilerp is c0*(1-fz) + c1*fy (fy, not fz).

#define BLOCK 256
#define NTAB  (16*524288)
#define PITCH 88   // ushort pitch: multiple of 8 (b128 alignment), 88 -> <=2-way write banks

constexpr int      kNL[16] = {16,22,28,37,49,65,85,112,148,195,257,338,446,589,777,1025};
constexpr unsigned kSZ[16] = {4096u,10648u,21952u,50656u,117656u,274632u,
                              524288u,524288u,524288u,524288u,524288u,
                              524288u,524288u,524288u,524288u,524288u};

typedef __attribute__((ext_vector_type(8))) short short8;
typedef __attribute__((ext_vector_type(4))) float float4v;

__device__ __forceinline__ short f2bf(float f) {
    unsigned u = __float_as_uint(f);
    unsigned r = u + 0x7fffu + ((u >> 16) & 1u);   // RNE
    return (short)(r >> 16);
}
__device__ __forceinline__ float bf2f(short h) {
    return __uint_as_float(((unsigned)(unsigned short)h) << 16);
}
__device__ __forceinline__ unsigned pk2(float a, float b) {
    return ((unsigned)(unsigned short)f2bf(b) << 16) | (unsigned)(unsigned short)f2bf(a);
}

// ================= prep kernels =================
__global__ void pack_pos(const float* __restrict__ x, float4* __restrict__ pos4, int n)
{
    int i = blockIdx.x * BLOCK + threadIdx.x;
    if (i >= n) return;
    const float* xr = x + (size_t)i * 19;
    pos4[i] = make_float4(xr[0], xr[1], xr[2], 0.f);
}

__global__ void conv_tables(const float* __restrict__ grids, ushort2* __restrict__ tbf)
{
    int i = blockIdx.x * BLOCK + threadIdx.x;
    if (i >= NTAB) return;
    float2 v = ((const float2*)grids)[i];
    ushort2 o;
    o.x = (unsigned short)f2bf(v.x);
    o.y = (unsigned short)f2bf(v.y);
    tbf[i] = o;
}

// Pack all weight B-frags in per-lane order. Frag f layout: wf[f*64 + lane].
// B-frag: B[k][n], n = lane&15, k = (lane>>4)*8 + j.
// Frags: 0-3 bw1[nt], 4-5 bw2[c], 6-9 bwc1[nt], 10-17 bwc2[c*4+nt], 18-19 bwc3[c].
__global__ void pack_wfrag(const float* __restrict__ w1, const float* __restrict__ w2,
                           const float* __restrict__ wc1, const float* __restrict__ wc2,
                           const float* __restrict__ wc3, uint4* __restrict__ wf)
{
    int lane = threadIdx.x;
    if (lane >= 64) return;
    int cn = lane & 15, q = lane >> 4;

    auto pack8 = [](const float* src, int stride) -> uint4 {
        uint4 r;
        r.x = pk2(src[0*stride], src[1*stride]);
        r.y = pk2(src[2*stride], src[3*stride]);
        r.z = pk2(src[4*stride], src[5*stride]);
        r.w = pk2(src[6*stride], src[7*stride]);
        return r;
    };

    int f = 0;
    for (int nt = 0; nt < 4; ++nt)
        wf[(f++)*64 + lane] = pack8(w1 + (q*8)*64 + nt*16 + cn, 64);
    for (int c = 0; c < 2; ++c)
        wf[(f++)*64 + lane] = pack8(w2 + (c*32 + q*8)*16 + cn, 16);
    for (int nt = 0; nt < 4; ++nt)
        wf[(f++)*64 + lane] = pack8(wc1 + (q*8)*64 + nt*16 + cn, 64);
    for (int c = 0; c < 2; ++c)
        for (int nt = 0; nt < 4; ++nt)
            wf[(f++)*64 + lane] = pack8(wc2 + (c*32 + q*8)*64 + nt*16 + cn, 64);
    for (int c = 0; c < 2; ++c) {
        if (cn < 3) wf[(f++)*64 + lane] = pack8(wc3 + (c*32 + q*8)*3 + cn, 3);
        else { uint4 z; z.x = z.y = z.z = z.w = 0u; wf[(f++)*64 + lane] = z; }
    }
}

// ================= encode =================
template<int L>
__device__ __forceinline__ void gather4(const float4* __restrict__ pos4,
                                        const ushort2* __restrict__ tbf,
                                        unsigned* __restrict__ encu,
                                        int n, int p0, int cnt)
{
    constexpr int R = kNL[L];
    constexpr unsigned S = kSZ[L];

    float fxa[4], fya[4];
    unsigned idx[4][8];
    #pragma unroll
    for (int q = 0; q < 4; ++q) {
        if (q >= cnt) continue;
        float4 p = pos4[p0+q];
        const float Rf = (float)R;
        float ux = p.x*Rf, uy = p.y*Rf, uz = p.z*Rf;
        float gx = floorf(ux), gy = floorf(uy), gz = floorf(uz);
        fxa[q] = ux-gx; fya[q] = uy-gy;
        int ix = (int)gx, iy = (int)gy, iz = (int)gz;
        #pragma unroll
        for (int j = 0; j < 8; ++j) {
            int ox = ix + ((j>>2)&1);
            int oy = iy + ((j>>1)&1);
            int oz = iz + (j&1);
            if (L <= 2) {
                idx[q][j] = (unsigned)((oz*(R*R) + oy*R + ox) % (int)S);
            } else {
                unsigned h = (unsigned)ox
                           ^ (unsigned)oy * 2654435761u
                           ^ (unsigned)oz * 805459861u;
                idx[q][j] = h % S;   // compile-time S -> magic mod
            }
        }
    }

    float2 v[4][8];
    #pragma unroll
    for (int q = 0; q < 4; ++q) {
        if (q >= cnt) continue;
        #pragma unroll
        for (int j = 0; j < 8; ++j) {
            ushort2 r = tbf[(size_t)L * 524288u + idx[q][j]];
            v[q][j] = make_float2(bf2f((short)r.x), bf2f((short)r.y));
        }
    }

    unsigned pkd[4];
    #pragma unroll
    for (int q = 0; q < 4; ++q) {
        if (q >= cnt) continue;
        const float fx = fxa[q], fy = fya[q];
        const float w0x = 1.f-fx, w0y = 1.f-fy;
        float e0, e1;
        {
            float c00 = v[q][0].x*w0x + v[q][4].x*fx;
            float c01 = v[q][1].x*w0x + v[q][5].x*fx;
            float c10 = v[q][2].x*w0x + v[q][6].x*fx;
            float c11 = v[q][3].x*w0x + v[q][7].x*fx;
            float c0 = c00*w0y + c10*fy;
            float c1 = c01*w0y + c11*fy;
            // reference bug: uses fy in place of fz (w0z = 1-fz still correct)
            float fz = ( (pos4[p0+q].z)*(float)R - floorf((pos4[p0+q].z)*(float)R) );
            e0 = c0*(1.f-fz) + c1*fy;
        }
        {
            float c00 = v[q][0].y*w0x + v[q][4].y*fx;
            float c01 = v[q][1].y*w0x + v[q][5].y*fx;
            float c10 = v[q][2].y*w0x + v[q][6].y*fx;
            float c11 = v[q][3].y*w0x + v[q][7].y*fx;
            float c0 = c00*w0y + c10*fy;
            float c1 = c01*w0y + c11*fy;
            float fz = ( (pos4[p0+q].z)*(float)R - floorf((pos4[p0+q].z)*(float)R) );
            e1 = c0*(1.f-fz) + c1*fy;
        }
        pkd[q] = pk2(e0, e1);
    }

    unsigned* d = encu + (size_t)L*n + p0;
    if (cnt == 4) {
        uint4 o; o.x = pkd[0]; o.y = pkd[1]; o.z = pkd[2]; o.w = pkd[3];
        *(uint4*)d = o;
    } else {
        for (int q = 0; q < cnt; ++q) d[q] = pkd[q];
    }
}

__global__ __launch_bounds__(BLOCK)
void enc_A(const float4* __restrict__ pos4, const ushort2* __restrict__ tbf,
           unsigned* __restrict__ encu, int n)
{
    int p0 = (blockIdx.y * BLOCK + threadIdx.x) * 4;
    if (p0 >= n) return;
    int cnt = min(4, n - p0);
    switch (blockIdx.x) {
        case 0: gather4< 6>(pos4,tbf,encu,n,p0,cnt); break;
        case 1: gather4< 7>(pos4,tbf,encu,n,p0,cnt); break;
        case 2: gather4< 8>(pos4,tbf,encu,n,p0,cnt); break;
        case 3: gather4< 9>(pos4,tbf,encu,n,p0,cnt); break;
        case 4: gather4<10>(pos4,tbf,encu,n,p0,cnt); break;
        case 5: gather4<11>(pos4,tbf,encu,n,p0,cnt); break;
        case 6: gather4<12>(pos4,tbf,encu,n,p0,cnt); break;
        case 7: gather4<13>(pos4,tbf,encu,n,p0,cnt); break;
    }
}

__global__ __launch_bounds__(BLOCK)
void enc_B(const float4* __restrict__ pos4, const ushort2* __restrict__ tbf,
           unsigned* __restrict__ encu, int n)
{
    int quarter = blockIdx.x & 3;
    int q = (n + 3) / 4;
    int jobBase = quarter * q;
    int jobEnd  = min(n, jobBase + q);
    int p0 = jobBase + (blockIdx.y * BLOCK + threadIdx.x) * 4;
    if (p0 >= jobEnd) return;
    int cnt = min(4, jobEnd - p0);
    if (blockIdx.x < 4) gather4<14>(pos4,tbf,encu,n,p0,cnt);
    else                gather4<15>(pos4,tbf,encu,n,p0,cnt);
}

__global__ __launch_bounds__(BLOCK)
void enc_C(const float4* __restrict__ pos4, const ushort2* __restrict__ tbf,
           unsigned* __restrict__ encu, int n)
{
    int p0 = (blockIdx.y * BLOCK + threadIdx.x) * 4;
    if (p0 >= n) return;
    int cnt = min(4, n - p0);
    switch (blockIdx.x) {
        case 0: gather4<0>(pos4,tbf,encu,n,p0,cnt); break;
        case 1: gather4<1>(pos4,tbf,encu,n,p0,cnt); break;
        case 2: gather4<2>(pos4,tbf,encu,n,p0,cnt); break;
        case 3: gather4<3>(pos4,tbf,encu,n,p0,cnt); break;
        case 4: gather4<4>(pos4,tbf,encu,n,p0,cnt); break;
        case 5: gather4<5>(pos4,tbf,encu,n,p0,cnt); break;
    }
}

// ================= MFMA MLP =================
// A-frag: A[m][k], m=lane&15 (point), k=(lane>>4)*8+j (feature).
// B-frag: B[k][n], n=lane&15, k=(lane>>4)*8+j  (pre-packed in wf).
// C/D:    row=(lane>>4)*4+r (point), col=lane&15.
__device__ __forceinline__ short8 ldfrag(const uint4* __restrict__ wf, int f, int lane) {
    union { uint4 u; short8 s; } cv;
    cv.u = wf[f*64 + lane];
    return cv.s;
}

__global__ __launch_bounds__(BLOCK)
void mlp_mfma(const float* __restrict__ x,
              const unsigned* __restrict__ encu,
              const uint4* __restrict__ wf,
              float* __restrict__ out, int n)
{
    __shared__ unsigned short s_scr[4][2][16*PITCH];  // per-wave hi/lo planes
    __shared__ float s_sig[4][16];
    __shared__ float s_col[4][16][4];

    const int t = threadIdx.x;
    const int lane = t & 63;
    const int wave = t >> 6;
    const int m = lane & 15;      // point-in-16 / B-col
    const int q = lane >> 4;      // quad
    const int cn = m;
    const int blk = blockIdx.x * 64;
    const int pt  = blk + wave*16 + m;
    const int ptc = pt < n ? pt : n - 1;

    const float4v zero = {0.f, 0.f, 0.f, 0.f};

    // ---- A-frag for L1: 4 dword loads from bf16 level planes ----
    union { unsigned u[4]; short8 s; } a1;
    #pragma unroll
    for (int i = 0; i < 4; ++i)
        a1.u[i] = encu[(size_t)(q*4 + i)*n + ptc];

    // ---- weight frags (first batch) ----
    short8 bw1[4], bw2[2], bwc1[4];
    #pragma unroll
    for (int nt = 0; nt < 4; ++nt) bw1[nt] = ldfrag(wf, nt, lane);
    #pragma unroll
    for (int c = 0; c < 2; ++c)    bw2[c]  = ldfrag(wf, 4 + c, lane);
    #pragma unroll
    for (int nt = 0; nt < 4; ++nt) bwc1[nt] = ldfrag(wf, 6 + nt, lane);

    // ---- L1: h(16pts x 64) = relu(enc @ w1) ----
    float4v h[4];
    #pragma unroll
    for (int nt = 0; nt < 4; ++nt) {
        h[nt] = __builtin_amdgcn_mfma_f32_16x16x32_bf16(a1.s, bw1[nt], zero, 0, 0, 0);
        #pragma unroll
        for (int r = 0; r < 4; ++r) h[nt][r] = fmaxf(h[nt][r], 0.f);
    }

    // ---- T1: h -> bf16 LDS [pt][feat], read back A-frags ----
    unsigned short* sA = &s_scr[wave][0][0];
    unsigned short* sB = &s_scr[wave][1][0];
    #pragma unroll
    for (int nt = 0; nt < 4; ++nt)
        #pragma unroll
        for (int r = 0; r < 4; ++r)
            sA[(q*4+r)*PITCH + nt*16 + cn] = (unsigned short)f2bf(h[nt][r]);
    short8 ah[2];
    #pragma unroll
    for (int c = 0; c < 2; ++c)
        ah[c] = *(const short8*)&sA[m*PITCH + c*32 + q*8];

    // ---- L2: o(16x16) = h @ w2 ----
    float4v o = __builtin_amdgcn_mfma_f32_16x16x32_bf16(ah[0], bw2[0], zero, 0, 0, 0);
    o = __builtin_amdgcn_mfma_f32_16x16x32_bf16(ah[1], bw2[1], o, 0, 0, 0);
    if (cn == 0) {
        #pragma unroll
        for (int r = 0; r < 4; ++r) s_sig[wave][q*4+r] = o[r];   // sigma column
    }

    // ---- CL1 input: [direc(16), o(16)] hi/lo ----
    // o -> bf16 LDS plane B, all lanes write, q>=2 lanes read their frag
    #pragma unroll
    for (int r = 0; r < 4; ++r)
        sB[(q*4+r)*PITCH + cn] = (unsigned short)f2bf(o[r]);
    short8 ov = *(const short8*)&sB[m*PITCH + (q >= 2 ? (q-2)*8 : 0)];

    union { unsigned u[4]; short8 s; } ci_hi, ci_lo;
    if (q < 2) {
        #pragma unroll
        for (int i = 0; i < 4; ++i) {
            float d0 = x[(size_t)ptc*19 + 3 + q*8 + 2*i];
            float d1 = x[(size_t)ptc*19 + 3 + q*8 + 2*i + 1];
            short h0 = f2bf(d0), h1 = f2bf(d1);
            ci_hi.u[i] = ((unsigned)(unsigned short)h1 << 16) | (unsigned)(unsigned short)h0;
            short l0 = f2bf(d0 - bf2f(h0)), l1 = f2bf(d1 - bf2f(h1));
            ci_lo.u[i] = ((unsigned)(unsigned short)l1 << 16) | (unsigned)(unsigned short)l0;
        }
    } else {
        ci_hi.s = ov;
        #pragma unroll
        for (int i = 0; i < 4; ++i) ci_lo.u[i] = 0u;
    }

    // ---- CL1: hc(16x64) = relu(ci @ wc1) ----
    float4v hc[4];
    #pragma unroll
    for (int nt = 0; nt < 4; ++nt) {
        hc[nt] = __builtin_amdgcn_mfma_f32_16x16x32_bf16(ci_hi.s, bwc1[nt], zero, 0, 0, 0);
        hc[nt] = __builtin_amdgcn_mfma_f32_16x16x32_bf16(ci_lo.s, bwc1[nt], hc[nt], 0, 0, 0);
        #pragma unroll
        for (int r = 0; r < 4; ++r) hc[nt][r] = fmaxf(hc[nt][r], 0.f);
    }

    // ---- weight frags (second batch) ----
    short8 bwc2[2][4], bwc3[2];
    #pragma unroll
    for (int c = 0; c < 2; ++c)
        #pragma unroll
        for (int nt = 0; nt < 4; ++nt)
            bwc2[c][nt] = ldfrag(wf, 10 + c*4 + nt, lane);
    #pragma unroll
    for (int c = 0; c < 2; ++c) bwc3[c] = ldfrag(wf, 18 + c, lane);

    // ---- T2: hc -> hi/lo bf16 LDS, read back ----
    #pragma unroll
    for (int nt = 0; nt < 4; ++nt)
        #pragma unroll
        for (int r = 0; r < 4; ++r) {
            float v = hc[nt][r];
            short hi = f2bf(v);
            sA[(q*4+r)*PITCH + nt*16 + cn] = (unsigned short)hi;
            sB[(q*4+r)*PITCH + nt*16 + cn] = (unsigned short)f2bf(v - bf2f(hi));
        }
    short8 ghi[2], glo[2];
    #pragma unroll
    for (int c = 0; c < 2; ++c) {
        ghi[c] = *(const short8*)&sA[m*PITCH + c*32 + q*8];
        glo[c] = *(const short8*)&sB[m*PITCH + c*32 + q*8];
    }

    // ---- CL2: g(16x64) = relu(hc @ wc2) ----
    float4v g[4];
    #pragma unroll
    for (int nt = 0; nt < 4; ++nt) {
        float4v acc = __builtin_amdgcn_mfma_f32_16x16x32_bf16(ghi[0], bwc2[0][nt], zero, 0, 0, 0);
        acc = __builtin_amdgcn_mfma_f32_16x16x32_bf16(glo[0], bwc2[0][nt], acc, 0, 0, 0);
        acc = __builtin_amdgcn_mfma_f32_16x16x32_bf16(ghi[1], bwc2[1][nt], acc, 0, 0, 0);
        acc = __builtin_amdgcn_mfma_f32_16x16x32_bf16(glo[1], bwc2[1][nt], acc, 0, 0, 0);
        #pragma unroll
        for (int r = 0; r < 4; ++r) acc[r] = fmaxf(acc[r], 0.f);
        g[nt] = acc;
    }

    // ---- T3: g -> hi/lo ----
    #pragma unroll
    for (int nt = 0; nt < 4; ++nt)
        #pragma unroll
        for (int r = 0; r < 4; ++r) {
            float v = g[nt][r];
            short hi = f2bf(v);
            sA[(q*4+r)*PITCH + nt*16 + cn] = (unsigned short)hi;
            sB[(q*4+r)*PITCH + nt*16 + cn] = (unsigned short)f2bf(v - bf2f(hi));
        }
    short8 uhi[2], ulo[2];
    #pragma unroll
    for (int c = 0; c < 2; ++c) {
        uhi[c] = *(const short8*)&sA[m*PITCH + c*32 + q*8];
        ulo[c] = *(const short8*)&sB[m*PITCH + c*32 + q*8];
    }

    // ---- CL3: colors = sigmoid(g @ wc3) ----
    float4v col = __builtin_amdgcn_mfma_f32_16x16x32_bf16(uhi[0], bwc3[0], zero, 0, 0, 0);
    col = __builtin_amdgcn_mfma_f32_16x16x32_bf16(ulo[0], bwc3[0], col, 0, 0, 0);
    col = __builtin_amdgcn_mfma_f32_16x16x32_bf16(uhi[1], bwc3[1], col, 0, 0, 0);
    col = __builtin_amdgcn_mfma_f32_16x16x32_bf16(ulo[1], bwc3[1], col, 0, 0, 0);
    #pragma unroll
    for (int r = 0; r < 4; ++r)
        col[r] = 1.f / (1.f + __expf(-col[r]));

    if (cn < 3) {
        #pragma unroll
        for (int r = 0; r < 4; ++r) s_col[wave][q*4+r][cn] = col[r];
    }

    // ---- store: 64 lanes write 16 points x 4 floats, coalesced ----
    __builtin_amdgcn_s_waitcnt(0);   // ensure LDS writes visible (same wave)
    int pfi = lane >> 2, c4 = lane & 3;
    int pout = blk + wave*16 + pfi;
    if (pout < n) {
        float v = (c4 == 3) ? s_sig[wave][pfi] : s_col[wave][pfi][c4];
        out[(size_t)pout*4 + c4] = v;
    }
}

// ================= launch =================
extern "C" void kernel_launch(void* const* d_in, const int* in_sizes, int n_in,
                              void* d_out, int out_size, void* d_ws, size_t ws_size,
                              hipStream_t stream) {
    const float* x     = (const float*)d_in[0];
    const float* grids = (const float*)d_in[1];
    const float* w1    = (const float*)d_in[2];
    const float* w2    = (const float*)d_in[3];
    const float* wc1   = (const float*)d_in[4];
    const float* wc2   = (const float*)d_in[5];
    const float* wc3   = (const float*)d_in[6];
    float* out = (float*)d_out;

    int n = in_sizes[0] / 19;
    size_t encB = (size_t)16 * n * sizeof(unsigned);       // 64 MB
    size_t posB = (size_t)n * sizeof(float4);              // 16 MB
    size_t tabB = (size_t)NTAB * sizeof(ushort2);          // 33.5 MB

    char* p = (char*)d_ws;
    unsigned* encu = (unsigned*)p;
    float4*   pos4 = (float4*)(p + encB);
    ushort2*  tbf  = (ushort2*)(p + encB + posB);
    uint4*    wf   = (uint4*)(p + encB + posB + tabB);

    pack_pos<<<(n + BLOCK - 1) / BLOCK, BLOCK, 0, stream>>>(x, pos4, n);
    conv_tables<<<(NTAB + BLOCK - 1) / BLOCK, BLOCK, 0, stream>>>(grids, tbf);
    pack_wfrag<<<1, 64, 0, stream>>>(w1, w2, wc1, wc2, wc3, wf);

    int nthread4 = (n + 3) / 4;
    int by  = (nthread4 + BLOCK - 1) / BLOCK;
    int qq  = (n + 3) / 4;
    int byB = ((qq + 3) / 4 + BLOCK - 1) / BLOCK;

    enc_A<<<dim3(8, by),  BLOCK, 0, stream>>>(pos4, tbf, encu, n);
    enc_B<<<dim3(8, byB), BLOCK, 0, stream>>>(pos4, tbf, encu, n);
    enc_C<<<dim3(6, by),  BLOCK, 0, stream>>>(pos4, tbf, encu, n);

    mlp_mfma<<<(n + 63) / 64, BLOCK, 0, stream>>>(x, encu, wf, out, n);
}

// Round 6
// 586.501 us; speedup vs baseline: 3.2139x; 1.2534x over previous
//
#include <hip/hip_runtime.h>
#include <math.h>

// Round 6:
//  - enc_A/B/C merged into one enc_all launch (phase-ordered blockIdx.y,
//    bx==XCD pinning preserved: linear block id = bx + 8*by).
//  - Hashed pow2 levels (6..15): when ix is even, x-corner pair hashes to
//    (h, h^1) -> one aligned 8B uint2 load serves both corners (4 instead of
//    8 requests/point for 50% of points).
//  - MLP / prep kernels unchanged from round 5.
// Reference bug replicated: final trilerp is c0*(1-fz) + c1*fy (fy, not fz).

#define BLOCK 256
#define NTAB  (16*524288)
#define PITCH 88

constexpr int      kNL[16] = {16,22,28,37,49,65,85,112,148,195,257,338,446,589,777,1025};
constexpr unsigned kSZ[16] = {4096u,10648u,21952u,50656u,117656u,274632u,
                              524288u,524288u,524288u,524288u,524288u,
                              524288u,524288u,524288u,524288u,524288u};

typedef __attribute__((ext_vector_type(8))) short short8;
typedef __attribute__((ext_vector_type(4))) float float4v;

__device__ __forceinline__ short f2bf(float f) {
    unsigned u = __float_as_uint(f);
    unsigned r = u + 0x7fffu + ((u >> 16) & 1u);   // RNE
    return (short)(r >> 16);
}
__device__ __forceinline__ float bf2f(short h) {
    return __uint_as_float(((unsigned)(unsigned short)h) << 16);
}
__device__ __forceinline__ unsigned pk2(float a, float b) {
    return ((unsigned)(unsigned short)f2bf(b) << 16) | (unsigned)(unsigned short)f2bf(a);
}
// packed table entry: lo16 = feat0, hi16 = feat1 (bf16)
__device__ __forceinline__ float pe0(unsigned u) { return __uint_as_float(u << 16); }
__device__ __forceinline__ float pe1(unsigned u) { return __uint_as_float(u & 0xffff0000u); }

// ================= prep kernels =================
__global__ void pack_pos(const float* __restrict__ x, float4* __restrict__ pos4, int n)
{
    int i = blockIdx.x * BLOCK + threadIdx.x;
    if (i >= n) return;
    const float* xr = x + (size_t)i * 19;
    pos4[i] = make_float4(xr[0], xr[1], xr[2], 0.f);
}

__global__ void conv_tables(const float* __restrict__ grids, unsigned* __restrict__ tbu)
{
    int i = blockIdx.x * BLOCK + threadIdx.x;
    if (i >= NTAB) return;
    float2 v = ((const float2*)grids)[i];
    tbu[i] = pk2(v.x, v.y);
}

// B-frag: B[k][n], n = lane&15, k = (lane>>4)*8 + j.
// Frags: 0-3 bw1[nt], 4-5 bw2[c], 6-9 bwc1[nt], 10-17 bwc2[c*4+nt], 18-19 bwc3[c].
__global__ void pack_wfrag(const float* __restrict__ w1, const float* __restrict__ w2,
                           const float* __restrict__ wc1, const float* __restrict__ wc2,
                           const float* __restrict__ wc3, uint4* __restrict__ wf)
{
    int lane = threadIdx.x;
    if (lane >= 64) return;
    int cn = lane & 15, q = lane >> 4;

    auto pack8 = [](const float* src, int stride) -> uint4 {
        uint4 r;
        r.x = pk2(src[0*stride], src[1*stride]);
        r.y = pk2(src[2*stride], src[3*stride]);
        r.z = pk2(src[4*stride], src[5*stride]);
        r.w = pk2(src[6*stride], src[7*stride]);
        return r;
    };

    int f = 0;
    for (int nt = 0; nt < 4; ++nt)
        wf[(f++)*64 + lane] = pack8(w1 + (q*8)*64 + nt*16 + cn, 64);
    for (int c = 0; c < 2; ++c)
        wf[(f++)*64 + lane] = pack8(w2 + (c*32 + q*8)*16 + cn, 16);
    for (int nt = 0; nt < 4; ++nt)
        wf[(f++)*64 + lane] = pack8(wc1 + (q*8)*64 + nt*16 + cn, 64);
    for (int c = 0; c < 2; ++c)
        for (int nt = 0; nt < 4; ++nt)
            wf[(f++)*64 + lane] = pack8(wc2 + (c*32 + q*8)*64 + nt*16 + cn, 64);
    for (int c = 0; c < 2; ++c) {
        if (cn < 3) wf[(f++)*64 + lane] = pack8(wc3 + (c*32 + q*8)*3 + cn, 3);
        else { uint4 z; z.x = z.y = z.z = z.w = 0u; wf[(f++)*64 + lane] = z; }
    }
}

// ================= encode =================
template<int L>
__device__ __forceinline__ void gather4(const float4* __restrict__ pos4,
                                        const unsigned* __restrict__ tball,
                                        unsigned* __restrict__ encu,
                                        int n, int p0, int cnt)
{
    constexpr int R = kNL[L];
    constexpr unsigned S = kSZ[L];
    constexpr unsigned H2c = 2654435761u, H3c = 805459861u;
    const unsigned* __restrict__ tbu = tball + (size_t)L * 524288u;

    unsigned vv[4][8];
    float fxa[4], fya[4], fza[4];
    #pragma unroll
    for (int q = 0; q < 4; ++q) {
        if (q >= cnt) continue;
        float4 p = pos4[p0+q];
        const float Rf = (float)R;
        float ux = p.x*Rf, uy = p.y*Rf, uz = p.z*Rf;
        float gx = floorf(ux), gy = floorf(uy), gz = floorf(uz);
        fxa[q] = ux-gx; fya[q] = uy-gy; fza[q] = uz-gz;
        int ix = (int)gx, iy = (int)gy, iz = (int)gz;

        if (L >= 6) {
            // pow2 hashed: x-pair trick when ix even
            unsigned tc[4];
            #pragma unroll
            for (int c = 0; c < 4; ++c) {
                int yb = c >> 1, zb = c & 1;
                tc[c] = (unsigned)(iy+yb)*H2c ^ (unsigned)(iz+zb)*H3c;
            }
            if ((ix & 1) == 0) {
                #pragma unroll
                for (int c = 0; c < 4; ++c) {
                    unsigned idx0 = ((unsigned)ix ^ tc[c]) & (S-1u);
                    uint2 pr = *(const uint2*)(tbu + (idx0 & ~1u));
                    unsigned swp = idx0 & 1u;
                    vv[q][c]   = swp ? pr.y : pr.x;   // corner x=ix
                    vv[q][4+c] = swp ? pr.x : pr.y;   // corner x=ix+1
                }
            } else {
                #pragma unroll
                for (int c = 0; c < 4; ++c) {
                    unsigned idx0 = ((unsigned)ix     ^ tc[c]) & (S-1u);
                    unsigned idx1 = ((unsigned)(ix+1) ^ tc[c]) & (S-1u);
                    vv[q][c]   = tbu[idx0];
                    vv[q][4+c] = tbu[idx1];
                }
            }
        } else if (L >= 3) {
            // non-pow2 hashed
            #pragma unroll
            for (int j = 0; j < 8; ++j) {
                int ox = ix + ((j>>2)&1);
                int oy = iy + ((j>>1)&1);
                int oz = iz + (j&1);
                unsigned h = (unsigned)ox ^ (unsigned)oy*H2c ^ (unsigned)oz*H3c;
                vv[q][j] = tbu[h % S];   // compile-time S -> magic mod
            }
        } else {
            // direct-indexed
            #pragma unroll
            for (int j = 0; j < 8; ++j) {
                int ox = ix + ((j>>2)&1);
                int oy = iy + ((j>>1)&1);
                int oz = iz + (j&1);
                vv[q][j] = tbu[(unsigned)((oz*(R*R) + oy*R + ox) % (int)S)];
            }
        }
    }

    unsigned pkd[4];
    #pragma unroll
    for (int q = 0; q < 4; ++q) {
        if (q >= cnt) continue;
        const float fx = fxa[q], fy = fya[q], fz = fza[q];
        const float w0x = 1.f-fx, w0y = 1.f-fy, w0z = 1.f-fz;
        float e0, e1;
        {
            float c00 = pe0(vv[q][0])*w0x + pe0(vv[q][4])*fx;
            float c01 = pe0(vv[q][1])*w0x + pe0(vv[q][5])*fx;
            float c10 = pe0(vv[q][2])*w0x + pe0(vv[q][6])*fx;
            float c11 = pe0(vv[q][3])*w0x + pe0(vv[q][7])*fx;
            float c0 = c00*w0y + c10*fy;
            float c1 = c01*w0y + c11*fy;
            e0 = c0*w0z + c1*fy;   // reference bug: fy (not fz)
        }
        {
            float c00 = pe1(vv[q][0])*w0x + pe1(vv[q][4])*fx;
            float c01 = pe1(vv[q][1])*w0x + pe1(vv[q][5])*fx;
            float c10 = pe1(vv[q][2])*w0x + pe1(vv[q][6])*fx;
            float c11 = pe1(vv[q][3])*w0x + pe1(vv[q][7])*fx;
            float c0 = c00*w0y + c10*fy;
            float c1 = c01*w0y + c11*fy;
            e1 = c0*w0z + c1*fy;   // reference bug: fy (not fz)
        }
        pkd[q] = pk2(e0, e1);
    }

    unsigned* d = encu + (size_t)L*n + p0;
    if (cnt == 4) {
        uint4 o; o.x = pkd[0]; o.y = pkd[1]; o.z = pkd[2]; o.w = pkd[3];
        *(uint4*)d = o;
    } else {
        for (int q = 0; q < cnt; ++q) d[q] = pkd[q];
    }
}

// merged encode: phase A (levels 6..13 XCD-pinned), phase B (14/15 on 4 XCDs
// each, quarter points), phase C (levels 0..5, any XCD).
__global__ __launch_bounds__(BLOCK)
void enc_all(const float4* __restrict__ pos4, const unsigned* __restrict__ tball,
             unsigned* __restrict__ encu, int n, int byA, int byB)
{
    const int bx = blockIdx.x;   // == XCD (linear id % 8)
    const int by = blockIdx.y;

    if (by < byA) {
        int p0 = (by*BLOCK + threadIdx.x) * 4;
        if (p0 >= n) return;
        int cnt = min(4, n - p0);
        switch (bx) {
            case 0: gather4< 6>(pos4,tball,encu,n,p0,cnt); break;
            case 1: gather4< 7>(pos4,tball,encu,n,p0,cnt); break;
            case 2: gather4< 8>(pos4,tball,encu,n,p0,cnt); break;
            case 3: gather4< 9>(pos4,tball,encu,n,p0,cnt); break;
            case 4: gather4<10>(pos4,tball,encu,n,p0,cnt); break;
            case 5: gather4<11>(pos4,tball,encu,n,p0,cnt); break;
            case 6: gather4<12>(pos4,tball,encu,n,p0,cnt); break;
            case 7: gather4<13>(pos4,tball,encu,n,p0,cnt); break;
        }
    } else if (by < byA + byB) {
        int q4 = (n + 3) / 4;
        int quarter = bx & 3;
        int jb = quarter * q4;
        int je = min(n, jb + q4);
        int p0 = jb + ((by-byA)*BLOCK + threadIdx.x) * 4;
        if (p0 >= je) return;
        int cnt = min(4, je - p0);
        if (bx < 4) gather4<14>(pos4,tball,encu,n,p0,cnt);
        else        gather4<15>(pos4,tball,encu,n,p0,cnt);
    } else {
        int cj = (by - byA - byB)*8 + bx;
        if (cj >= 6*byA) return;
        int level = cj % 6;
        int chunk = cj / 6;
        int p0 = (chunk*BLOCK + threadIdx.x) * 4;
        if (p0 >= n) return;
        int cnt = min(4, n - p0);
        switch (level) {
            case 0: gather4<0>(pos4,tball,encu,n,p0,cnt); break;
            case 1: gather4<1>(pos4,tball,encu,n,p0,cnt); break;
            case 2: gather4<2>(pos4,tball,encu,n,p0,cnt); break;
            case 3: gather4<3>(pos4,tball,encu,n,p0,cnt); break;
            case 4: gather4<4>(pos4,tball,encu,n,p0,cnt); break;
            case 5: gather4<5>(pos4,tball,encu,n,p0,cnt); break;
        }
    }
}

// ================= MFMA MLP (unchanged from round 5) =================
__device__ __forceinline__ short8 ldfrag(const uint4* __restrict__ wf, int f, int lane) {
    union { uint4 u; short8 s; } cv;
    cv.u = wf[f*64 + lane];
    return cv.s;
}

__global__ __launch_bounds__(BLOCK)
void mlp_mfma(const float* __restrict__ x,
              const unsigned* __restrict__ encu,
              const uint4* __restrict__ wf,
              float* __restrict__ out, int n)
{
    __shared__ unsigned short s_scr[4][2][16*PITCH];
    __shared__ float s_sig[4][16];
    __shared__ float s_col[4][16][4];

    const int t = threadIdx.x;
    const int lane = t & 63;
    const int wave = t >> 6;
    const int m = lane & 15;
    const int q = lane >> 4;
    const int cn = m;
    const int blk = blockIdx.x * 64;
    const int pt  = blk + wave*16 + m;
    const int ptc = pt < n ? pt : n - 1;

    const float4v zero = {0.f, 0.f, 0.f, 0.f};

    union { unsigned u[4]; short8 s; } a1;
    #pragma unroll
    for (int i = 0; i < 4; ++i)
        a1.u[i] = encu[(size_t)(q*4 + i)*n + ptc];

    short8 bw1[4], bw2[2], bwc1[4];
    #pragma unroll
    for (int nt = 0; nt < 4; ++nt) bw1[nt] = ldfrag(wf, nt, lane);
    #pragma unroll
    for (int c = 0; c < 2; ++c)    bw2[c]  = ldfrag(wf, 4 + c, lane);
    #pragma unroll
    for (int nt = 0; nt < 4; ++nt) bwc1[nt] = ldfrag(wf, 6 + nt, lane);

    float4v h[4];
    #pragma unroll
    for (int nt = 0; nt < 4; ++nt) {
        h[nt] = __builtin_amdgcn_mfma_f32_16x16x32_bf16(a1.s, bw1[nt], zero, 0, 0, 0);
        #pragma unroll
        for (int r = 0; r < 4; ++r) h[nt][r] = fmaxf(h[nt][r], 0.f);
    }

    unsigned short* sA = &s_scr[wave][0][0];
    unsigned short* sB = &s_scr[wave][1][0];
    #pragma unroll
    for (int nt = 0; nt < 4; ++nt)
        #pragma unroll
        for (int r = 0; r < 4; ++r)
            sA[(q*4+r)*PITCH + nt*16 + cn] = (unsigned short)f2bf(h[nt][r]);
    short8 ah[2];
    #pragma unroll
    for (int c = 0; c < 2; ++c)
        ah[c] = *(const short8*)&sA[m*PITCH + c*32 + q*8];

    float4v o = __builtin_amdgcn_mfma_f32_16x16x32_bf16(ah[0], bw2[0], zero, 0, 0, 0);
    o = __builtin_amdgcn_mfma_f32_16x16x32_bf16(ah[1], bw2[1], o, 0, 0, 0);
    if (cn == 0) {
        #pragma unroll
        for (int r = 0; r < 4; ++r) s_sig[wave][q*4+r] = o[r];
    }

    #pragma unroll
    for (int r = 0; r < 4; ++r)
        sB[(q*4+r)*PITCH + cn] = (unsigned short)f2bf(o[r]);
    short8 ov = *(const short8*)&sB[m*PITCH + (q >= 2 ? (q-2)*8 : 0)];

    union { unsigned u[4]; short8 s; } ci_hi, ci_lo;
    if (q < 2) {
        #pragma unroll
        for (int i = 0; i < 4; ++i) {
            float d0 = x[(size_t)ptc*19 + 3 + q*8 + 2*i];
            float d1 = x[(size_t)ptc*19 + 3 + q*8 + 2*i + 1];
            short h0 = f2bf(d0), h1 = f2bf(d1);
            ci_hi.u[i] = ((unsigned)(unsigned short)h1 << 16) | (unsigned)(unsigned short)h0;
            short l0 = f2bf(d0 - bf2f(h0)), l1 = f2bf(d1 - bf2f(h1));
            ci_lo.u[i] = ((unsigned)(unsigned short)l1 << 16) | (unsigned)(unsigned short)l0;
        }
    } else {
        ci_hi.s = ov;
        #pragma unroll
        for (int i = 0; i < 4; ++i) ci_lo.u[i] = 0u;
    }

    float4v hc[4];
    #pragma unroll
    for (int nt = 0; nt < 4; ++nt) {
        hc[nt] = __builtin_amdgcn_mfma_f32_16x16x32_bf16(ci_hi.s, bwc1[nt], zero, 0, 0, 0);
        hc[nt] = __builtin_amdgcn_mfma_f32_16x16x32_bf16(ci_lo.s, bwc1[nt], hc[nt], 0, 0, 0);
        #pragma unroll
        for (int r = 0; r < 4; ++r) hc[nt][r] = fmaxf(hc[nt][r], 0.f);
    }

    short8 bwc2[2][4], bwc3[2];
    #pragma unroll
    for (int c = 0; c < 2; ++c)
        #pragma unroll
        for (int nt = 0; nt < 4; ++nt)
            bwc2[c][nt] = ldfrag(wf, 10 + c*4 + nt, lane);
    #pragma unroll
    for (int c = 0; c < 2; ++c) bwc3[c] = ldfrag(wf, 18 + c, lane);

    #pragma unroll
    for (int nt = 0; nt < 4; ++nt)
        #pragma unroll
        for (int r = 0; r < 4; ++r) {
            float v = hc[nt][r];
            short hi = f2bf(v);
            sA[(q*4+r)*PITCH + nt*16 + cn] = (unsigned short)hi;
            sB[(q*4+r)*PITCH + nt*16 + cn] = (unsigned short)f2bf(v - bf2f(hi));
        }
    short8 ghi[2], glo[2];
    #pragma unroll
    for (int c = 0; c < 2; ++c) {
        ghi[c] = *(const short8*)&sA[m*PITCH + c*32 + q*8];
        glo[c] = *(const short8*)&sB[m*PITCH + c*32 + q*8];
    }

    float4v g[4];
    #pragma unroll
    for (int nt = 0; nt < 4; ++nt) {
        float4v acc = __builtin_amdgcn_mfma_f32_16x16x32_bf16(ghi[0], bwc2[0][nt], zero, 0, 0, 0);
        acc = __builtin_amdgcn_mfma_f32_16x16x32_bf16(glo[0], bwc2[0][nt], acc, 0, 0, 0);
        acc = __builtin_amdgcn_mfma_f32_16x16x32_bf16(ghi[1], bwc2[1][nt], acc, 0, 0, 0);
        acc = __builtin_amdgcn_mfma_f32_16x16x32_bf16(glo[1], bwc2[1][nt], acc, 0, 0, 0);
        #pragma unroll
        for (int r = 0; r < 4; ++r) acc[r] = fmaxf(acc[r], 0.f);
        g[nt] = acc;
    }

    #pragma unroll
    for (int nt = 0; nt < 4; ++nt)
        #pragma unroll
        for (int r = 0; r < 4; ++r) {
            float v = g[nt][r];
            short hi = f2bf(v);
            sA[(q*4+r)*PITCH + nt*16 + cn] = (unsigned short)hi;
            sB[(q*4+r)*PITCH + nt*16 + cn] = (unsigned short)f2bf(v - bf2f(hi));
        }
    short8 uhi[2], ulo[2];
    #pragma unroll
    for (int c = 0; c < 2; ++c) {
        uhi[c] = *(const short8*)&sA[m*PITCH + c*32 + q*8];
        ulo[c] = *(const short8*)&sB[m*PITCH + c*32 + q*8];
    }

    float4v col = __builtin_amdgcn_mfma_f32_16x16x32_bf16(uhi[0], bwc3[0], zero, 0, 0, 0);
    col = __builtin_amdgcn_mfma_f32_16x16x32_bf16(ulo[0], bwc3[0], col, 0, 0, 0);
    col = __builtin_amdgcn_mfma_f32_16x16x32_bf16(uhi[1], bwc3[1], col, 0, 0, 0);
    col = __builtin_amdgcn_mfma_f32_16x16x32_bf16(ulo[1], bwc3[1], col, 0, 0, 0);
    #pragma unroll
    for (int r = 0; r < 4; ++r)
        col[r] = 1.f / (1.f + __expf(-col[r]));

    if (cn < 3) {
        #pragma unroll
        for (int r = 0; r < 4; ++r) s_col[wave][q*4+r][cn] = col[r];
    }

    __builtin_amdgcn_s_waitcnt(0);
    int pfi = lane >> 2, c4 = lane & 3;
    int pout = blk + wave*16 + pfi;
    if (pout < n) {
        float v = (c4 == 3) ? s_sig[wave][pfi] : s_col[wave][pfi][c4];
        out[(size_t)pout*4 + c4] = v;
    }
}

// ================= launch =================
extern "C" void kernel_launch(void* const* d_in, const int* in_sizes, int n_in,
                              void* d_out, int out_size, void* d_ws, size_t ws_size,
                              hipStream_t stream) {
    const float* x     = (const float*)d_in[0];
    const float* grids = (const float*)d_in[1];
    const float* w1    = (const float*)d_in[2];
    const float* w2    = (const float*)d_in[3];
    const float* wc1   = (const float*)d_in[4];
    const float* wc2   = (const float*)d_in[5];
    const float* wc3   = (const float*)d_in[6];
    float* out = (float*)d_out;

    int n = in_sizes[0] / 19;
    size_t encB = (size_t)16 * n * sizeof(unsigned);       // 64 MB
    size_t posB = (size_t)n * sizeof(float4);              // 16 MB
    size_t tabB = (size_t)NTAB * sizeof(unsigned);         // 33.5 MB

    char* p = (char*)d_ws;
    unsigned* encu = (unsigned*)p;
    float4*   pos4 = (float4*)(p + encB);
    unsigned* tbu  = (unsigned*)(p + encB + posB);
    uint4*    wf   = (uint4*)(p + encB + posB + tabB);

    pack_pos<<<(n + BLOCK - 1) / BLOCK, BLOCK, 0, stream>>>(x, pos4, n);
    conv_tables<<<(NTAB + BLOCK - 1) / BLOCK, BLOCK, 0, stream>>>(grids, tbu);
    pack_wfrag<<<1, 64, 0, stream>>>(w1, w2, wc1, wc2, wc3, wf);

    int byA = (n + BLOCK*4 - 1) / (BLOCK*4);          // chunks of 1024 points
    int q4  = (n + 3) / 4;
    int byB = (q4 + BLOCK*4 - 1) / (BLOCK*4);
    int jobsC = 6 * byA;
    int byC = (jobsC + 7) / 8;
    dim3 ge(8, byA + byB + byC);
    enc_all<<<ge, BLOCK, 0, stream>>>(pos4, tbu, encu, n, byA, byB);

    mlp_mfma<<<(n + 63) / 64, BLOCK, 0, stream>>>(x, encu, wf, out, n);
}